// Round 3
// baseline (588.835 us; speedup 1.0000x reference)
//
#include <hip/hip_runtime.h>
#include <hip/hip_bf16.h>
#include <stdint.h>

// Problem dims (fixed by the reference)
constexpr int Mdim = 256;    // batch
constexpr int Ndim = 4096;   // codes E
constexpr int Kdim = 16384;  // EMB

typedef __attribute__((ext_vector_type(8))) short short8;  // 8 x bf16 (4 VGPR)
typedef __attribute__((ext_vector_type(4))) float f32x4;

// ---------- swizzled-layout GEMM config (fast path) ----------
constexpr int KS2  = 8;             // split-K
constexpr int KC2  = Kdim / KS2;    // 2048
constexpr int BK2  = 64;            // K per LDS tile
constexpr int NIT2 = KC2 / BK2;     // 32
// swizzled tile: [oct 8][row 128][8 elems] bf16 = 16 KB, contiguous
constexpr int TILE_ELEMS = 8 * 128 * 8;  // 8192

// ws layout (bytes)
constexpr size_t E_SWZ_OFF = 0;
constexpr size_t E_SWZ_SZ  = (size_t)Ndim * Kdim * 2;           // 128 MiB
constexpr size_t X_SWZ_OFF = E_SWZ_OFF + E_SWZ_SZ;
constexpr size_t X_SWZ_SZ  = (size_t)Mdim * Kdim * 2;           // 8 MiB
constexpr size_t ESQ_OFF   = X_SWZ_OFF + X_SWZ_SZ;
constexpr size_t ESQ_SZ    = (size_t)Ndim * 4;                  // 16 KiB
constexpr size_t PART_OFF  = ESQ_OFF + ESQ_SZ;
constexpr size_t PART_SZ   = (size_t)KS2 * Mdim * Ndim * 4;     // 32 MiB
constexpr size_t NEED_FAST = PART_OFF + PART_SZ;                // ~168 MiB

// middle tier (round-2 fused path): partials only
constexpr int KS_MID = 16;
constexpr size_t NEED_MID = (size_t)KS_MID * Mdim * Ndim * 4;   // 64 MiB

// packed fp32x2 -> bf16x2 RNE (v_cvt_pk_bf16_f32 on gfx950)
__device__ __forceinline__ unsigned int cvt2(float lo, float hi) {
  union { __hip_bfloat162 h; unsigned int u; } v;
  v.h = __float22bfloat162_rn(make_float2(lo, hi));
  return v.u;
}

__device__ __forceinline__ void async16(const void* g, void* l) {
  __builtin_amdgcn_global_load_lds(
      (const __attribute__((address_space(1))) void*)g,
      (__attribute__((address_space(3))) void*)l, 16, 0, 0);
}

// ============================================================
// Pass 1: fp32 -> bf16 convert + fragment-tile swizzle + ||e||^2
// Block covers 4 consecutive rows (full-line 64B dst cells).
// Blocks [0,1024): e rows;  [1024,1088): x rows.
// ============================================================
__global__ __launch_bounds__(256) void k_convert(const float* __restrict__ x,
                                                 const float* __restrict__ e,
                                                 unsigned short* __restrict__ e_swz,
                                                 unsigned short* __restrict__ x_swz,
                                                 float* __restrict__ esq) {
  __shared__ float red[256];
  const int b = blockIdx.x;
  const bool is_x = (b >= Ndim / 4);
  const int row0 = (is_x ? (b - Ndim / 4) : b) * 4;
  const float* src = is_x ? (x + (size_t)row0 * Kdim) : (e + (size_t)row0 * Kdim);
  unsigned short* dst = is_x ? x_swz : e_swz;
  const int nt = row0 >> 7;       // 128-row tile index
  const int rBase = row0 & 127;
  const int t = threadIdx.x;
  const int NKC = Kdim / 64;      // 256 k-chunks per row

  float sq[4] = {0.f, 0.f, 0.f, 0.f};
#pragma unroll
  for (int i = 0; i < 8; ++i) {
    int g = i * 256 + t;          // cell-group: kc = g>>3, oct = g&7
    int kc = g >> 3, oct = g & 7;
    int koff = kc * 64 + oct * 8;
    unsigned short* dcell = dst + ((((size_t)nt * NKC + kc) * 8 + oct) * 128 + rBase) * 8;
#pragma unroll
    for (int rr = 0; rr < 4; ++rr) {
      const float4* s4 = (const float4*)(src + (size_t)rr * Kdim + koff);
      float4 a = s4[0], c = s4[1];
      sq[rr] += a.x * a.x + a.y * a.y + a.z * a.z + a.w * a.w
              + c.x * c.x + c.y * c.y + c.z * c.z + c.w * c.w;
      union { short8 s; unsigned int u[4]; } p;
      p.u[0] = cvt2(a.x, a.y); p.u[1] = cvt2(a.z, a.w);
      p.u[2] = cvt2(c.x, c.y); p.u[3] = cvt2(c.z, c.w);
      *(short8*)(dcell + rr * 8) = p.s;
    }
  }
  if (!is_x) {
#pragma unroll
    for (int rr = 0; rr < 4; ++rr) {
      red[t] = sq[rr];
      __syncthreads();
      for (int s = 128; s > 0; s >>= 1) {
        if (t < s) red[t] += red[t + s];
        __syncthreads();
      }
      if (t == 0) esq[row0 + rr] = red[0];
      __syncthreads();
    }
  }
}

// ============================================================
// Pass 2: bf16 MFMA GEMM over swizzled tiles, global_load_lds staging.
// part[z][m][n] = (z==0 ? ||e_n||^2 : 0) - 2 * x.e |_kchunk(z)
// ============================================================
__global__ __launch_bounds__(256) void k_gemm_swz(const unsigned short* __restrict__ x_swz,
                                                  const unsigned short* __restrict__ e_swz,
                                                  const float* __restrict__ esq,
                                                  float* __restrict__ part) {
  __shared__ unsigned short lds[2][2][8][128][8];  // [buf][A/B][oct][row][8] = 64 KiB
  const int t = threadIdx.x;
  const int nb = blockIdx.x;   // 0..31
  const int mb = blockIdx.y;   // 0..1
  const int kz = blockIdx.z;   // 0..7
  const int NKC = Kdim / 64;
  const int kc0 = kz * NIT2;

  const int wave = t >> 6, lane = t & 63;
  const int wm = (wave & 1) * 64, wn = (wave >> 1) * 64;
  const int lcol = lane & 15, quad = lane >> 4;

  const unsigned short* Asrc = x_swz + ((size_t)mb * NKC + kc0) * TILE_ELEMS;
  const unsigned short* Bsrc = e_swz + ((size_t)nb * NKC + kc0) * TILE_ELEMS;

  auto stage = [&](int buf, int it) {
    const unsigned short* a = Asrc + (size_t)it * TILE_ELEMS;
    const unsigned short* bsc = Bsrc + (size_t)it * TILE_ELEMS;
#pragma unroll
    for (int j = 0; j < 4; ++j) {
      int cell = j * 256 + t;
      async16(a + (size_t)cell * 8,  &lds[buf][0][0][0][0] + cell * 8);
      async16(bsc + (size_t)cell * 8, &lds[buf][1][0][0][0] + cell * 8);
    }
  };

  f32x4 acc[4][4] = {};
  stage(0, 0);
  __syncthreads();  // vmcnt drain -> buf0 ready

  for (int it = 0; it < NIT2; ++it) {
    const int cur = it & 1;
    if (it + 1 < NIT2) stage(cur ^ 1, it + 1);  // async into other buffer
    short8 af[2][4], bf[2][4];
#pragma unroll
    for (int s = 0; s < 2; ++s) {
      const int oct = s * 4 + quad;
#pragma unroll
      for (int mi = 0; mi < 4; ++mi)
        af[s][mi] = *(const short8*)&lds[cur][0][oct][wm + mi * 16 + lcol][0];
#pragma unroll
      for (int ni = 0; ni < 4; ++ni)
        bf[s][ni] = *(const short8*)&lds[cur][1][oct][wn + ni * 16 + lcol][0];
    }
#pragma unroll
    for (int s = 0; s < 2; ++s)
#pragma unroll
      for (int mi = 0; mi < 4; ++mi)
#pragma unroll
        for (int ni = 0; ni < 4; ++ni)
          acc[mi][ni] = __builtin_amdgcn_mfma_f32_16x16x32_bf16(af[s][mi], bf[s][ni], acc[mi][ni], 0, 0, 0);
    __syncthreads();  // drains async loads (next buf ready) + fences frag reads
  }

  // epilogue: C/D layout col=lane&15, row=quad*4+reg
  const int m0 = mb * 128, n0 = nb * 128;
  float* base = part + (size_t)kz * Mdim * Ndim;
  float ev[4];
#pragma unroll
  for (int ni = 0; ni < 4; ++ni)
    ev[ni] = (kz == 0) ? esq[n0 + wn + ni * 16 + lcol] : 0.0f;
#pragma unroll
  for (int mi = 0; mi < 4; ++mi)
#pragma unroll
    for (int ni = 0; ni < 4; ++ni)
#pragma unroll
      for (int reg = 0; reg < 4; ++reg) {
        int row = m0 + wm + mi * 16 + quad * 4 + reg;
        int cl  = wn + ni * 16 + lcol;
        base[(size_t)row * Ndim + n0 + cl] = ev[ni] - 2.0f * acc[mi][ni][reg];
      }
}

// ============================================================
// Fused select: split-K reduce (compile-time NZ, unrolled) + top-2
// + exact fp32 refine + one-hot write
// ============================================================
template <int NZ>
__global__ __launch_bounds__(256) void k_select_t(const float* __restrict__ part,
                                                  const float* __restrict__ x,
                                                  const float* __restrict__ e,
                                                  float* __restrict__ out) {
  __shared__ float sv1[256], sv2[256];
  __shared__ int   si1[256], si2[256];
  __shared__ float s1[256], s2[256];
  __shared__ int win_sh;
  const int b = blockIdx.x, t = threadIdx.x;

  float v1 = 3.4e38f, v2 = 3.4e38f; int i1 = 0, i2 = 1;
  auto upd = [&](float v, int idx) {
    if (v < v1)      { v2 = v1; i2 = i1; v1 = v; i1 = idx; }
    else if (v < v2) { v2 = v;  i2 = idx; }
  };
#pragma unroll
  for (int i = 0; i < Ndim / 4 / 256; ++i) {
    int q = t + i * 256;  // float4 index over n
    float sx = 0.f, sy = 0.f, sz = 0.f, sw = 0.f;
#pragma unroll
    for (int z = 0; z < NZ; ++z) {
      float4 v = ((const float4*)part)[((size_t)z * Mdim + b) * (Ndim / 4) + q];
      sx += v.x; sy += v.y; sz += v.z; sw += v.w;
    }
    upd(sx, 4 * q + 0); upd(sy, 4 * q + 1); upd(sz, 4 * q + 2); upd(sw, 4 * q + 3);
  }
  sv1[t] = v1; si1[t] = i1; sv2[t] = v2; si2[t] = i2;
  __syncthreads();
  for (int sOff = 128; sOff > 0; sOff >>= 1) {
    if (t < sOff) {
      float bv1 = sv1[t + sOff], bv2 = sv2[t + sOff];
      int   bi1 = si1[t + sOff], bi2 = si2[t + sOff];
      float av1 = sv1[t],        av2 = sv2[t];
      int   ai1 = si1[t],        ai2 = si2[t];
      if (bv1 < av1)      { av2 = av1; ai2 = ai1; av1 = bv1; ai1 = bi1; }
      else if (bv1 < av2) { av2 = bv1; ai2 = bi1; }
      if (bv2 < av2)      { av2 = bv2; ai2 = bi2; }
      sv1[t] = av1; si1[t] = ai1; sv2[t] = av2; si2[t] = ai2;
    }
    __syncthreads();
  }
  const int c1 = si1[0], c2 = si2[0];

  // exact fp32 distances for the two candidates
  const float4* xb = (const float4*)(x + (size_t)b  * Kdim);
  const float4* e1 = (const float4*)(e + (size_t)c1 * Kdim);
  const float4* e2 = (const float4*)(e + (size_t)c2 * Kdim);
  float a1 = 0.f, a2 = 0.f;
#pragma unroll 4
  for (int i = 0; i < Kdim / 4 / 256; ++i) {
    int q = t + i * 256;
    float4 xv  = xb[q];
    float4 ev1 = e1[q];
    float4 ev2 = e2[q];
    a1 += ev1.x * (ev1.x - 2.f * xv.x) + ev1.y * (ev1.y - 2.f * xv.y)
        + ev1.z * (ev1.z - 2.f * xv.z) + ev1.w * (ev1.w - 2.f * xv.w);
    a2 += ev2.x * (ev2.x - 2.f * xv.x) + ev2.y * (ev2.y - 2.f * xv.y)
        + ev2.z * (ev2.z - 2.f * xv.z) + ev2.w * (ev2.w - 2.f * xv.w);
  }
  s1[t] = a1; s2[t] = a2;
  __syncthreads();
  for (int sOff = 128; sOff > 0; sOff >>= 1) {
    if (t < sOff) { s1[t] += s1[t + sOff]; s2[t] += s2[t + sOff]; }
    __syncthreads();
  }
  if (t == 0) {
    float d1 = s1[0], d2 = s2[0];
    win_sh = (d2 < d1 || (d2 == d1 && c2 < c1)) ? c2 : c1;  // np.argmin tie: smaller idx
  }
  __syncthreads();

  const int win = win_sh;
  float* outb = out + (size_t)b * Ndim;
#pragma unroll
  for (int g = 0; g < 4; ++g) {
    int q = g * 256 + t;
    float4 v;
    v.x = (win == 4 * q + 0) ? 1.f : 0.f;
    v.y = (win == 4 * q + 1) ? 1.f : 0.f;
    v.z = (win == 4 * q + 2) ? 1.f : 0.f;
    v.w = (win == 4 * q + 3) ? 1.f : 0.f;
    ((float4*)outb)[q] = v;
  }
}

// ============================================================
// Fallback tiers (round-2 fused gemm): used when ws is small.
// ============================================================
constexpr int FMT = 128, FNT = 128, FBK = 32;

__global__ __launch_bounds__(256) void k_gemm_fused(const float* __restrict__ x,
                                                    const float* __restrict__ e,
                                                    float* __restrict__ dst,
                                                    int ws_mode) {
  __shared__ short lds[2][2][4][128][8];
  __shared__ float esq_part[256];
  __shared__ float esq_sh[128];
  const int t  = threadIdx.x;
  const int n0 = blockIdx.x * FNT;
  const int m0 = blockIdx.y * FMT;
  const int kz = blockIdx.z;
  const int KCF = Kdim / KS_MID;
  const int NITF = KCF / FBK;
  const int k0 = kz * KCF;
  const int r  = t >> 1;
  const int kq = (t & 1) * 16;
  const int g0 = (t & 1) * 2;
  const float* xp = x + (size_t)(m0 + r) * Kdim + k0 + kq;
  const float* ep = e + (size_t)(n0 + r) * Kdim + k0 + kq;
  const int wave = t >> 6, lane = t & 63;
  const int wm = (wave & 1) * 64, wn = (wave >> 1) * 64;
  const int lcol = lane & 15, quad = lane >> 4;

  f32x4 acc[4][4] = {};
  float esq_acc = 0.0f;
  float4 bufA[4], bufB[4];
#pragma unroll
  for (int g = 0; g < 4; ++g) {
    bufA[g] = ((const float4*)xp)[g];
    bufB[g] = ((const float4*)ep)[g];
  }
  auto stagef = [&](int buf) {
    union { short8 s; unsigned int u[4]; } pa0, pa1, pb0, pb1;
    pa0.u[0] = cvt2(bufA[0].x, bufA[0].y); pa0.u[1] = cvt2(bufA[0].z, bufA[0].w);
    pa0.u[2] = cvt2(bufA[1].x, bufA[1].y); pa0.u[3] = cvt2(bufA[1].z, bufA[1].w);
    pa1.u[0] = cvt2(bufA[2].x, bufA[2].y); pa1.u[1] = cvt2(bufA[2].z, bufA[2].w);
    pa1.u[2] = cvt2(bufA[3].x, bufA[3].y); pa1.u[3] = cvt2(bufA[3].z, bufA[3].w);
    pb0.u[0] = cvt2(bufB[0].x, bufB[0].y); pb0.u[1] = cvt2(bufB[0].z, bufB[0].w);
    pb0.u[2] = cvt2(bufB[1].x, bufB[1].y); pb0.u[3] = cvt2(bufB[1].z, bufB[1].w);
    pb1.u[0] = cvt2(bufB[2].x, bufB[2].y); pb1.u[1] = cvt2(bufB[2].z, bufB[2].w);
    pb1.u[2] = cvt2(bufB[3].x, bufB[3].y); pb1.u[3] = cvt2(bufB[3].z, bufB[3].w);
#pragma unroll
    for (int g = 0; g < 4; ++g)
      esq_acc += bufB[g].x * bufB[g].x + bufB[g].y * bufB[g].y
               + bufB[g].z * bufB[g].z + bufB[g].w * bufB[g].w;
    *(short8*)&lds[buf][0][g0    ][r][0] = pa0.s;
    *(short8*)&lds[buf][0][g0 + 1][r][0] = pa1.s;
    *(short8*)&lds[buf][1][g0    ][r][0] = pb0.s;
    *(short8*)&lds[buf][1][g0 + 1][r][0] = pb1.s;
  };
  stagef(0);
  __syncthreads();
  for (int it = 0; it < NITF; ++it) {
    const int cur = it & 1;
    if (it + 1 < NITF) {
      const float* xn = xp + (size_t)(it + 1) * FBK;
      const float* en = ep + (size_t)(it + 1) * FBK;
#pragma unroll
      for (int g = 0; g < 4; ++g) {
        bufA[g] = ((const float4*)xn)[g];
        bufB[g] = ((const float4*)en)[g];
      }
    }
    short8 af[4], bfr[4];
#pragma unroll
    for (int mi = 0; mi < 4; ++mi)
      af[mi] = *(const short8*)&lds[cur][0][quad][wm + mi * 16 + lcol][0];
#pragma unroll
    for (int ni = 0; ni < 4; ++ni)
      bfr[ni] = *(const short8*)&lds[cur][1][quad][wn + ni * 16 + lcol][0];
#pragma unroll
    for (int mi = 0; mi < 4; ++mi)
#pragma unroll
      for (int ni = 0; ni < 4; ++ni)
        acc[mi][ni] = __builtin_amdgcn_mfma_f32_16x16x32_bf16(af[mi], bfr[ni], acc[mi][ni], 0, 0, 0);
    if (it + 1 < NITF) {
      stagef(cur ^ 1);
      __syncthreads();
    }
  }
  esq_part[t] = esq_acc;
  __syncthreads();
  if (t < 128) esq_sh[t] = esq_part[2 * t] + esq_part[2 * t + 1];
  __syncthreads();
  if (ws_mode) {
    float* base = dst + (size_t)kz * Mdim * Ndim;
#pragma unroll
    for (int mi = 0; mi < 4; ++mi)
#pragma unroll
      for (int ni = 0; ni < 4; ++ni)
#pragma unroll
        for (int reg = 0; reg < 4; ++reg) {
          int row = m0 + wm + mi * 16 + quad * 4 + reg;
          int cl  = wn + ni * 16 + lcol;
          base[(size_t)row * Ndim + n0 + cl] = esq_sh[cl] - 2.0f * acc[mi][ni][reg];
        }
  } else {
#pragma unroll
    for (int mi = 0; mi < 4; ++mi)
#pragma unroll
      for (int ni = 0; ni < 4; ++ni)
#pragma unroll
        for (int reg = 0; reg < 4; ++reg) {
          int row = m0 + wm + mi * 16 + quad * 4 + reg;
          int cl  = wn + ni * 16 + lcol;
          atomicAdd(&dst[(size_t)row * Ndim + n0 + cl], esq_sh[cl] - 2.0f * acc[mi][ni][reg]);
        }
  }
}

extern "C" void kernel_launch(void* const* d_in, const int* in_sizes, int n_in,
                              void* d_out, int out_size, void* d_ws, size_t ws_size,
                              hipStream_t stream) {
  (void)in_sizes; (void)n_in; (void)out_size;
  const float* x = (const float*)d_in[0];  // [256, 16384] fp32
  const float* e = (const float*)d_in[1];  // [4096, 16384] fp32
  float* out = (float*)d_out;
  char* ws = (char*)d_ws;

  if (ws_size >= NEED_FAST) {
    unsigned short* e_swz = (unsigned short*)(ws + E_SWZ_OFF);
    unsigned short* x_swz = (unsigned short*)(ws + X_SWZ_OFF);
    float* esq  = (float*)(ws + ESQ_OFF);
    float* part = (float*)(ws + PART_OFF);
    hipLaunchKernelGGL(k_convert, dim3(Ndim / 4 + Mdim / 4), dim3(256), 0, stream,
                       x, e, e_swz, x_swz, esq);
    hipLaunchKernelGGL(k_gemm_swz, dim3(Ndim / 128, Mdim / 128, KS2), dim3(256), 0, stream,
                       x_swz, e_swz, esq, part);
    hipLaunchKernelGGL(k_select_t<KS2>, dim3(Mdim), dim3(256), 0, stream, part, x, e, out);
  } else if (ws_size >= NEED_MID) {
    float* part = (float*)ws;
    hipLaunchKernelGGL(k_gemm_fused, dim3(Ndim / FNT, Mdim / FMT, KS_MID), dim3(256), 0, stream,
                       x, e, part, 1);
    hipLaunchKernelGGL(k_select_t<KS_MID>, dim3(Mdim), dim3(256), 0, stream, part, x, e, out);
  } else {
    hipMemsetAsync(d_out, 0, (size_t)Mdim * Ndim * sizeof(float), stream);
    hipLaunchKernelGGL(k_gemm_fused, dim3(Ndim / FNT, Mdim / FMT, KS_MID), dim3(256), 0, stream,
                       x, e, out, 0);
    hipLaunchKernelGGL(k_select_t<1>, dim3(Mdim), dim3(256), 0, stream, out, x, e, out);
  }
}

// Round 4
// 455.304 us; speedup vs baseline: 1.2933x; 1.2933x over previous
//
#include <hip/hip_runtime.h>
#include <hip/hip_bf16.h>
#include <stdint.h>

// Problem dims (fixed by the reference)
constexpr int Mdim = 256;    // batch
constexpr int Ndim = 4096;   // codes E
constexpr int Kdim = 16384;  // EMB

typedef __attribute__((ext_vector_type(8))) short short8;  // 8 x bf16 (4 VGPR)
typedef __attribute__((ext_vector_type(4))) float f32x4;

// ---------- swizzled-layout GEMM config (fast path) ----------
constexpr int KS2  = 8;             // split-K
constexpr int KC2  = Kdim / KS2;    // 2048
constexpr int BK2  = 64;            // K per LDS tile
constexpr int NIT2 = KC2 / BK2;     // 32
constexpr int NKC  = Kdim / 64;     // 256 k-chunks per row
// swizzled tile: [oct 8][row 128][8 elems] bf16 = 16 KB, contiguous
constexpr int TILE_ELEMS = 8 * 128 * 8;  // 8192

// ws layout (bytes)
constexpr size_t E_SWZ_OFF = 0;
constexpr size_t E_SWZ_SZ  = (size_t)Ndim * Kdim * 2;           // 128 MiB
constexpr size_t X_SWZ_OFF = E_SWZ_OFF + E_SWZ_SZ;
constexpr size_t X_SWZ_SZ  = (size_t)Mdim * Kdim * 2;           // 8 MiB
constexpr size_t ESQ_OFF   = X_SWZ_OFF + X_SWZ_SZ;
constexpr size_t ESQ_SZ    = (size_t)Ndim * 4;                  // 16 KiB
constexpr size_t PART_OFF  = ESQ_OFF + ESQ_SZ;
constexpr size_t PART_SZ   = (size_t)KS2 * Mdim * Ndim * 4;     // 32 MiB
constexpr size_t NEED_FAST = PART_OFF + PART_SZ;                // ~168 MiB

// middle tier (round-2 fused path): partials only
constexpr int KS_MID = 16;
constexpr size_t NEED_MID = (size_t)KS_MID * Mdim * Ndim * 4;   // 64 MiB

// packed fp32x2 -> bf16x2 RNE (v_cvt_pk_bf16_f32 on gfx950)
__device__ __forceinline__ unsigned int cvt2(float lo, float hi) {
  union { __hip_bfloat162 h; unsigned int u; } v;
  v.h = __float22bfloat162_rn(make_float2(lo, hi));
  return v.u;
}

__device__ __forceinline__ void async16(const void* g, void* l) {
  __builtin_amdgcn_global_load_lds(
      (const __attribute__((address_space(1))) void*)g,
      (__attribute__((address_space(3))) void*)l, 16, 0, 0);
}

// ============================================================
// Pass 1 (v2): fp32 -> bf16 convert + fragment-tile swizzle + ||e||^2.
// Block = 128 rows x 256 k panel.
//   reads : 1 KB contiguous per row  (thread = half row, 32 seq float4)
//   writes: 4 adjacent cells = one sequential 64 KiB block store
// Blocks [0, 2048): e (nt = b>>6, p = b&63); [2048, 2176): x.
// ============================================================
__global__ __launch_bounds__(256) void k_convert(const float* __restrict__ x,
                                                 const float* __restrict__ e,
                                                 unsigned short* __restrict__ e_swz,
                                                 unsigned short* __restrict__ x_swz,
                                                 float* __restrict__ esq) {
  __shared__ unsigned short sw[4][8][128][8];  // [kc_l][oct][row][8] = 64 KiB
  const int b = blockIdx.x;
  const bool is_x = (b >= 2048);
  const int idx = is_x ? (b - 2048) : b;
  const int nt = idx >> 6;        // tile (e: 0..31, x: 0..1)
  const int p  = idx & 63;        // 256-k panel
  const float* src = is_x ? x : e;
  unsigned short* dst = is_x ? x_swz : e_swz;

  const int t = threadIdx.x;
  const int r = t >> 1;           // row within 128-tile
  const int h = t & 1;            // half of the 256-k panel

  const float4* s4 = (const float4*)(src + (size_t)(nt * 128 + r) * Kdim + p * 256 + h * 128);
  float4 v[32];
#pragma unroll
  for (int g = 0; g < 32; ++g) v[g] = s4[g];   // 512 B sequential per thread

  float sq = 0.0f;
#pragma unroll
  for (int c = 0; c < 16; ++c) {  // 8-elem chunks: k_local = h*128 + c*8
    const int kc_l = h * 2 + (c >> 3);
    const int oct  = c & 7;
    float4 a = v[2 * c], d = v[2 * c + 1];
    sq += a.x * a.x + a.y * a.y + a.z * a.z + a.w * a.w
        + d.x * d.x + d.y * d.y + d.z * d.z + d.w * d.w;
    union { short8 s; unsigned int u[4]; } pk;
    pk.u[0] = cvt2(a.x, a.y); pk.u[1] = cvt2(a.z, a.w);
    pk.u[2] = cvt2(d.x, d.y); pk.u[3] = cvt2(d.z, d.w);
    *(short8*)&sw[kc_l][oct][r][0] = pk.s;
  }

  if (!is_x) {
    float tot = sq + __shfl_xor(sq, 1, 64);
    if (h == 0) atomicAdd(&esq[nt * 128 + r], tot);
  }
  __syncthreads();

  // sequential 64 KiB block store: cells (nt, p*4 .. p*4+3) are adjacent
  const size_t base = ((size_t)nt * NKC + (size_t)p * 4) * TILE_ELEMS;  // in shorts
  const float4* lsrc = (const float4*)&sw[0][0][0][0];
  float4* gdst = (float4*)(dst + base);
#pragma unroll
  for (int i = 0; i < 16; ++i) gdst[i * 256 + t] = lsrc[i * 256 + t];
}

// ============================================================
// Pass 2: bf16 MFMA GEMM over swizzled tiles, global_load_lds staging.
// part[z][m][n] = (z==0 ? ||e_n||^2 : 0) - 2 * x.e |_kchunk(z)
// ============================================================
__global__ __launch_bounds__(256) void k_gemm_swz(const unsigned short* __restrict__ x_swz,
                                                  const unsigned short* __restrict__ e_swz,
                                                  const float* __restrict__ esq,
                                                  float* __restrict__ part) {
  __shared__ unsigned short lds[2][2][8][128][8];  // [buf][A/B][oct][row][8] = 64 KiB
  const int t = threadIdx.x;
  const int nb = blockIdx.x;   // 0..31
  const int mb = blockIdx.y;   // 0..1
  const int kz = blockIdx.z;   // 0..7
  const int kc0 = kz * NIT2;

  const int wave = t >> 6, lane = t & 63;
  const int wm = (wave & 1) * 64, wn = (wave >> 1) * 64;
  const int lcol = lane & 15, quad = lane >> 4;

  const unsigned short* Asrc = x_swz + ((size_t)mb * NKC + kc0) * TILE_ELEMS;
  const unsigned short* Bsrc = e_swz + ((size_t)nb * NKC + kc0) * TILE_ELEMS;

  auto stage = [&](int buf, int it) {
    const unsigned short* a = Asrc + (size_t)it * TILE_ELEMS;
    const unsigned short* bsc = Bsrc + (size_t)it * TILE_ELEMS;
#pragma unroll
    for (int j = 0; j < 4; ++j) {
      int cell = j * 256 + t;
      async16(a + (size_t)cell * 8,  &lds[buf][0][0][0][0] + cell * 8);
      async16(bsc + (size_t)cell * 8, &lds[buf][1][0][0][0] + cell * 8);
    }
  };

  f32x4 acc[4][4] = {};
  stage(0, 0);
  __syncthreads();  // vmcnt drain -> buf0 ready

  for (int it = 0; it < NIT2; ++it) {
    const int cur = it & 1;
    if (it + 1 < NIT2) stage(cur ^ 1, it + 1);  // async into other buffer
    short8 af[2][4], bf[2][4];
#pragma unroll
    for (int s = 0; s < 2; ++s) {
      const int oct = s * 4 + quad;
#pragma unroll
      for (int mi = 0; mi < 4; ++mi)
        af[s][mi] = *(const short8*)&lds[cur][0][oct][wm + mi * 16 + lcol][0];
#pragma unroll
      for (int ni = 0; ni < 4; ++ni)
        bf[s][ni] = *(const short8*)&lds[cur][1][oct][wn + ni * 16 + lcol][0];
    }
#pragma unroll
    for (int s = 0; s < 2; ++s)
#pragma unroll
      for (int mi = 0; mi < 4; ++mi)
#pragma unroll
        for (int ni = 0; ni < 4; ++ni)
          acc[mi][ni] = __builtin_amdgcn_mfma_f32_16x16x32_bf16(af[s][mi], bf[s][ni], acc[mi][ni], 0, 0, 0);
    __syncthreads();  // drains async loads (next buf ready) + fences frag reads
  }

  // epilogue: C/D layout col=lane&15, row=quad*4+reg
  const int m0 = mb * 128, n0 = nb * 128;
  float* base = part + (size_t)kz * Mdim * Ndim;
  float ev[4];
#pragma unroll
  for (int ni = 0; ni < 4; ++ni)
    ev[ni] = (kz == 0) ? esq[n0 + wn + ni * 16 + lcol] : 0.0f;
#pragma unroll
  for (int mi = 0; mi < 4; ++mi)
#pragma unroll
    for (int ni = 0; ni < 4; ++ni)
#pragma unroll
      for (int reg = 0; reg < 4; ++reg) {
        int row = m0 + wm + mi * 16 + quad * 4 + reg;
        int cl  = wn + ni * 16 + lcol;
        base[(size_t)row * Ndim + n0 + cl] = ev[ni] - 2.0f * acc[mi][ni][reg];
      }
}

// ============================================================
// Fused select: split-K reduce (compile-time NZ, unrolled) + top-2
// + exact fp32 refine + one-hot write
// ============================================================
template <int NZ>
__global__ __launch_bounds__(256) void k_select_t(const float* __restrict__ part,
                                                  const float* __restrict__ x,
                                                  const float* __restrict__ e,
                                                  float* __restrict__ out) {
  __shared__ float sv1[256], sv2[256];
  __shared__ int   si1[256], si2[256];
  __shared__ float s1[256], s2[256];
  __shared__ int win_sh;
  const int b = blockIdx.x, t = threadIdx.x;

  float v1 = 3.4e38f, v2 = 3.4e38f; int i1 = 0, i2 = 1;
  auto upd = [&](float v, int idx) {
    if (v < v1)      { v2 = v1; i2 = i1; v1 = v; i1 = idx; }
    else if (v < v2) { v2 = v;  i2 = idx; }
  };
#pragma unroll
  for (int i = 0; i < Ndim / 4 / 256; ++i) {
    int q = t + i * 256;  // float4 index over n
    float sx = 0.f, sy = 0.f, sz = 0.f, sw = 0.f;
#pragma unroll
    for (int z = 0; z < NZ; ++z) {
      float4 v = ((const float4*)part)[((size_t)z * Mdim + b) * (Ndim / 4) + q];
      sx += v.x; sy += v.y; sz += v.z; sw += v.w;
    }
    upd(sx, 4 * q + 0); upd(sy, 4 * q + 1); upd(sz, 4 * q + 2); upd(sw, 4 * q + 3);
  }
  sv1[t] = v1; si1[t] = i1; sv2[t] = v2; si2[t] = i2;
  __syncthreads();
  for (int sOff = 128; sOff > 0; sOff >>= 1) {
    if (t < sOff) {
      float bv1 = sv1[t + sOff], bv2 = sv2[t + sOff];
      int   bi1 = si1[t + sOff], bi2 = si2[t + sOff];
      float av1 = sv1[t],        av2 = sv2[t];
      int   ai1 = si1[t],        ai2 = si2[t];
      if (bv1 < av1)      { av2 = av1; ai2 = ai1; av1 = bv1; ai1 = bi1; }
      else if (bv1 < av2) { av2 = bv1; ai2 = bi1; }
      if (bv2 < av2)      { av2 = bv2; ai2 = bi2; }
      sv1[t] = av1; si1[t] = ai1; sv2[t] = av2; si2[t] = ai2;
    }
    __syncthreads();
  }
  const int c1 = si1[0], c2 = si2[0];

  // exact fp32 distances for the two candidates
  const float4* xb = (const float4*)(x + (size_t)b  * Kdim);
  const float4* e1 = (const float4*)(e + (size_t)c1 * Kdim);
  const float4* e2 = (const float4*)(e + (size_t)c2 * Kdim);
  float a1 = 0.f, a2 = 0.f;
#pragma unroll 4
  for (int i = 0; i < Kdim / 4 / 256; ++i) {
    int q = t + i * 256;
    float4 xv  = xb[q];
    float4 ev1 = e1[q];
    float4 ev2 = e2[q];
    a1 += ev1.x * (ev1.x - 2.f * xv.x) + ev1.y * (ev1.y - 2.f * xv.y)
        + ev1.z * (ev1.z - 2.f * xv.z) + ev1.w * (ev1.w - 2.f * xv.w);
    a2 += ev2.x * (ev2.x - 2.f * xv.x) + ev2.y * (ev2.y - 2.f * xv.y)
        + ev2.z * (ev2.z - 2.f * xv.z) + ev2.w * (ev2.w - 2.f * xv.w);
  }
  s1[t] = a1; s2[t] = a2;
  __syncthreads();
  for (int sOff = 128; sOff > 0; sOff >>= 1) {
    if (t < sOff) { s1[t] += s1[t + sOff]; s2[t] += s2[t + sOff]; }
    __syncthreads();
  }
  if (t == 0) {
    float d1 = s1[0], d2 = s2[0];
    win_sh = (d2 < d1 || (d2 == d1 && c2 < c1)) ? c2 : c1;  // np.argmin tie: smaller idx
  }
  __syncthreads();

  const int win = win_sh;
  float* outb = out + (size_t)b * Ndim;
#pragma unroll
  for (int g = 0; g < 4; ++g) {
    int q = g * 256 + t;
    float4 v;
    v.x = (win == 4 * q + 0) ? 1.f : 0.f;
    v.y = (win == 4 * q + 1) ? 1.f : 0.f;
    v.z = (win == 4 * q + 2) ? 1.f : 0.f;
    v.w = (win == 4 * q + 3) ? 1.f : 0.f;
    ((float4*)outb)[q] = v;
  }
}

// ============================================================
// Fallback tiers (round-2 fused gemm): used when ws is small.
// ============================================================
constexpr int FMT = 128, FNT = 128, FBK = 32;

__global__ __launch_bounds__(256) void k_gemm_fused(const float* __restrict__ x,
                                                    const float* __restrict__ e,
                                                    float* __restrict__ dst,
                                                    int ws_mode) {
  __shared__ short lds[2][2][4][128][8];
  __shared__ float esq_part[256];
  __shared__ float esq_sh[128];
  const int t  = threadIdx.x;
  const int n0 = blockIdx.x * FNT;
  const int m0 = blockIdx.y * FMT;
  const int kz = blockIdx.z;
  const int KCF = Kdim / KS_MID;
  const int NITF = KCF / FBK;
  const int k0 = kz * KCF;
  const int r  = t >> 1;
  const int kq = (t & 1) * 16;
  const int g0 = (t & 1) * 2;
  const float* xp = x + (size_t)(m0 + r) * Kdim + k0 + kq;
  const float* ep = e + (size_t)(n0 + r) * Kdim + k0 + kq;
  const int wave = t >> 6, lane = t & 63;
  const int wm = (wave & 1) * 64, wn = (wave >> 1) * 64;
  const int lcol = lane & 15, quad = lane >> 4;

  f32x4 acc[4][4] = {};
  float esq_acc = 0.0f;
  float4 bufA[4], bufB[4];
#pragma unroll
  for (int g = 0; g < 4; ++g) {
    bufA[g] = ((const float4*)xp)[g];
    bufB[g] = ((const float4*)ep)[g];
  }
  auto stagef = [&](int buf) {
    union { short8 s; unsigned int u[4]; } pa0, pa1, pb0, pb1;
    pa0.u[0] = cvt2(bufA[0].x, bufA[0].y); pa0.u[1] = cvt2(bufA[0].z, bufA[0].w);
    pa0.u[2] = cvt2(bufA[1].x, bufA[1].y); pa0.u[3] = cvt2(bufA[1].z, bufA[1].w);
    pa1.u[0] = cvt2(bufA[2].x, bufA[2].y); pa1.u[1] = cvt2(bufA[2].z, bufA[2].w);
    pa1.u[2] = cvt2(bufA[3].x, bufA[3].y); pa1.u[3] = cvt2(bufA[3].z, bufA[3].w);
    pb0.u[0] = cvt2(bufB[0].x, bufB[0].y); pb0.u[1] = cvt2(bufB[0].z, bufB[0].w);
    pb0.u[2] = cvt2(bufB[1].x, bufB[1].y); pb0.u[3] = cvt2(bufB[1].z, bufB[1].w);
    pb1.u[0] = cvt2(bufB[2].x, bufB[2].y); pb1.u[1] = cvt2(bufB[2].z, bufB[2].w);
    pb1.u[2] = cvt2(bufB[3].x, bufB[3].y); pb1.u[3] = cvt2(bufB[3].z, bufB[3].w);
#pragma unroll
    for (int g = 0; g < 4; ++g)
      esq_acc += bufB[g].x * bufB[g].x + bufB[g].y * bufB[g].y
               + bufB[g].z * bufB[g].z + bufB[g].w * bufB[g].w;
    *(short8*)&lds[buf][0][g0    ][r][0] = pa0.s;
    *(short8*)&lds[buf][0][g0 + 1][r][0] = pa1.s;
    *(short8*)&lds[buf][1][g0    ][r][0] = pb0.s;
    *(short8*)&lds[buf][1][g0 + 1][r][0] = pb1.s;
  };
  stagef(0);
  __syncthreads();
  for (int it = 0; it < NITF; ++it) {
    const int cur = it & 1;
    if (it + 1 < NITF) {
      const float* xn = xp + (size_t)(it + 1) * FBK;
      const float* en = ep + (size_t)(it + 1) * FBK;
#pragma unroll
      for (int g = 0; g < 4; ++g) {
        bufA[g] = ((const float4*)xn)[g];
        bufB[g] = ((const float4*)en)[g];
      }
    }
    short8 af[4], bfr[4];
#pragma unroll
    for (int mi = 0; mi < 4; ++mi)
      af[mi] = *(const short8*)&lds[cur][0][quad][wm + mi * 16 + lcol][0];
#pragma unroll
    for (int ni = 0; ni < 4; ++ni)
      bfr[ni] = *(const short8*)&lds[cur][1][quad][wn + ni * 16 + lcol][0];
#pragma unroll
    for (int mi = 0; mi < 4; ++mi)
#pragma unroll
      for (int ni = 0; ni < 4; ++ni)
        acc[mi][ni] = __builtin_amdgcn_mfma_f32_16x16x32_bf16(af[mi], bfr[ni], acc[mi][ni], 0, 0, 0);
    if (it + 1 < NITF) {
      stagef(cur ^ 1);
      __syncthreads();
    }
  }
  esq_part[t] = esq_acc;
  __syncthreads();
  if (t < 128) esq_sh[t] = esq_part[2 * t] + esq_part[2 * t + 1];
  __syncthreads();
  if (ws_mode) {
    float* base = dst + (size_t)kz * Mdim * Ndim;
#pragma unroll
    for (int mi = 0; mi < 4; ++mi)
#pragma unroll
      for (int ni = 0; ni < 4; ++ni)
#pragma unroll
        for (int reg = 0; reg < 4; ++reg) {
          int row = m0 + wm + mi * 16 + quad * 4 + reg;
          int cl  = wn + ni * 16 + lcol;
          base[(size_t)row * Ndim + n0 + cl] = esq_sh[cl] - 2.0f * acc[mi][ni][reg];
        }
  } else {
#pragma unroll
    for (int mi = 0; mi < 4; ++mi)
#pragma unroll
      for (int ni = 0; ni < 4; ++ni)
#pragma unroll
        for (int reg = 0; reg < 4; ++reg) {
          int row = m0 + wm + mi * 16 + quad * 4 + reg;
          int cl  = wn + ni * 16 + lcol;
          atomicAdd(&dst[(size_t)row * Ndim + n0 + cl], esq_sh[cl] - 2.0f * acc[mi][ni][reg]);
        }
  }
}

extern "C" void kernel_launch(void* const* d_in, const int* in_sizes, int n_in,
                              void* d_out, int out_size, void* d_ws, size_t ws_size,
                              hipStream_t stream) {
  (void)in_sizes; (void)n_in; (void)out_size;
  const float* x = (const float*)d_in[0];  // [256, 16384] fp32
  const float* e = (const float*)d_in[1];  // [4096, 16384] fp32
  float* out = (float*)d_out;
  char* ws = (char*)d_ws;

  if (ws_size >= NEED_FAST) {
    unsigned short* e_swz = (unsigned short*)(ws + E_SWZ_OFF);
    unsigned short* x_swz = (unsigned short*)(ws + X_SWZ_OFF);
    float* esq  = (float*)(ws + ESQ_OFF);
    float* part = (float*)(ws + PART_OFF);
    hipMemsetAsync(esq, 0, ESQ_SZ, stream);  // esq accumulated via atomics
    hipLaunchKernelGGL(k_convert, dim3(2048 + 128), dim3(256), 0, stream,
                       x, e, e_swz, x_swz, esq);
    hipLaunchKernelGGL(k_gemm_swz, dim3(Ndim / 128, Mdim / 128, KS2), dim3(256), 0, stream,
                       x_swz, e_swz, esq, part);
    hipLaunchKernelGGL(k_select_t<KS2>, dim3(Mdim), dim3(256), 0, stream, part, x, e, out);
  } else if (ws_size >= NEED_MID) {
    float* part = (float*)ws;
    hipLaunchKernelGGL(k_gemm_fused, dim3(Ndim / FNT, Mdim / FMT, KS_MID), dim3(256), 0, stream,
                       x, e, part, 1);
    hipLaunchKernelGGL(k_select_t<KS_MID>, dim3(Mdim), dim3(256), 0, stream, part, x, e, out);
  } else {
    hipMemsetAsync(d_out, 0, (size_t)Mdim * Ndim * sizeof(float), stream);
    hipLaunchKernelGGL(k_gemm_fused, dim3(Ndim / FNT, Mdim / FMT, KS_MID), dim3(256), 0, stream,
                       x, e, out, 0);
    hipLaunchKernelGGL(k_select_t<1>, dim3(Mdim), dim3(256), 0, stream, out, x, e, out);
  }
}